// Round 3
// baseline (348.400 us; speedup 1.0000x reference)
//
#include <hip/hip_runtime.h>
#include <stdint.h>

// Round 2:
//  attn: QBLK 32->64 (halves staging per unit work), one q-tile per block
//        (256 blocks = 8 batch x 32 tiles, makespan = t=31 block w/ 32 steps),
//        global_load_lds staging w/ inverse-swizzled global source (rule #21),
//        counted-vmcnt split pipeline: K(t+1) loads during softmax+PV(t),
//        V(t+1) loads during QK^T(t+1); vmcnt(8) waits, never 0 mid-loop.
//  gemm: XCD-chunked grid remap (XCD owns 16 m-tiles x all 12 (w,nt)) -> X L2-reuse.

typedef __attribute__((ext_vector_type(4))) float f32x4;
typedef __attribute__((ext_vector_type(8))) short short8;
typedef __attribute__((ext_vector_type(4))) short short4b;

__device__ __forceinline__ short f2bf(float f) {
    union { float f; uint32_t u; } v; v.f = f;
    uint32_t r = (v.u + 0x7FFFu + ((v.u >> 16) & 1u)) >> 16;   // RNE
    return (short)r;
}
__device__ __forceinline__ float bf2f(short s) {
    union { uint32_t u; float f; } v; v.u = ((uint32_t)(uint16_t)s) << 16; return v.f;
}
__device__ __forceinline__ float sigm(float x) { return 1.0f / (1.0f + __expf(-x)); }

__device__ __forceinline__ void gload_lds16(const void* g, void* l) {
    __builtin_amdgcn_global_load_lds(
        (const __attribute__((address_space(1))) void*)g,
        (__attribute__((address_space(3))) void*)l, 16, 0, 0);
}

// barriers that do NOT drain vmcnt (keep prefetches in flight)
#define BAR()      asm volatile("s_waitcnt lgkmcnt(0)\n\ts_barrier" ::: "memory")
#define SYNC_VM8() asm volatile("s_waitcnt vmcnt(8) lgkmcnt(0)\n\ts_barrier" ::: "memory")
#define SYNC_VM0() asm volatile("s_waitcnt vmcnt(0) lgkmcnt(0)\n\ts_barrier" ::: "memory")

// ---------------------------------------------------------------- K1: weights
__global__ __launch_bounds__(256) void prep_weights(
    const float* __restrict__ Wq, const float* __restrict__ Wv, const float* __restrict__ Wk,
    short* __restrict__ Wt)
{
    __shared__ float T[64 * 68];
    int bid = blockIdx.x;
    int w = bid >> 6;                 // 0..2
    int tile = bid & 63;
    int n0 = (tile & 7) * 64;
    int k0 = (tile >> 3) * 64;
    const float* W = (w == 0) ? Wq : (w == 1) ? Wv : Wk;
    int t = threadIdx.x;
    int tr = t >> 4, tc = t & 15;
    for (int rr = 0; rr < 4; ++rr) {
        int row = rr * 16 + tr;       // k-local
        float4 v = *reinterpret_cast<const float4*>(&W[(size_t)(k0 + row) * 512 + n0 + tc * 4]);
        T[row * 68 + tc * 4 + 0] = v.x;
        T[row * 68 + tc * 4 + 1] = v.y;
        T[row * 68 + tc * 4 + 2] = v.z;
        T[row * 68 + tc * 4 + 3] = v.w;
    }
    __syncthreads();
    for (int wr = 0; wr < 4; ++wr) {
        int nl = wr * 16 + tr;        // n-local
        short4b o;
        for (int i = 0; i < 4; ++i) o[i] = f2bf(T[(tc * 4 + i) * 68 + nl]);
        *reinterpret_cast<short4b*>(&Wt[((size_t)(w * 512 + n0 + nl)) * 512 + k0 + tc * 4]) = o;
    }
}

// ---------------------------------------------------------------- K2: QKV GEMM
// XCD-chunked: xcd=bid&7 owns m-tiles [16*xcd,16*xcd+16) x all 12 (w,nt) combos.
__global__ __launch_bounds__(256) void qkv_gemm(
    const float* __restrict__ X,     // [16384][512] fp32
    const short* __restrict__ Wt,    // [3][512 n][512 k] bf16
    short* __restrict__ Qb, short* __restrict__ Kb, short* __restrict__ VtG)
{
    __shared__ short SMEM[128 * 128];
    short* As = SMEM;
    short* Bs = SMEM + 128 * 64;

    int bx = blockIdx.x;
    int xcd = bx & 7;
    int l = bx >> 3;                  // 0..191
    int mt = xcd * 16 + l / 12;       // 0..127
    int yy = l % 12;
    int w = yy >> 2, nt = yy & 3;
    int m0 = mt * 128, n0 = nt * 128;

    int tid = threadIdx.x;
    int wid = tid >> 6, lane = tid & 63;
    int wr = wid >> 1, wc = wid & 1;
    int ln = lane & 15, hi = lane >> 4;

    f32x4 acc[4][4];
    for (int i = 0; i < 4; ++i) for (int j = 0; j < 4; ++j) acc[i][j] = {0.f, 0.f, 0.f, 0.f};

    const short* WtW = Wt + (size_t)w * 512 * 512;

    for (int ko = 0; ko < 8; ++ko) {
        int k0 = ko * 64;
        __syncthreads();
        for (int j = 0; j < 8; ++j) {
            int c = j * 256 + tid;
            int row = c >> 4, col4 = c & 15;
            float4 v = *reinterpret_cast<const float4*>(&X[(size_t)(m0 + row) * 512 + k0 + col4 * 4]);
            short4b s;
            s[0] = f2bf(v.x); s[1] = f2bf(v.y); s[2] = f2bf(v.z); s[3] = f2bf(v.w);
            *reinterpret_cast<short4b*>(&As[row * 64 + ((col4 * 4) ^ ((row & 7) << 3))]) = s;
        }
        for (int j = 0; j < 4; ++j) {
            int c = j * 256 + tid;
            int row = c >> 3, col8 = c & 7;
            short8 v = *reinterpret_cast<const short8*>(&WtW[(size_t)(n0 + row) * 512 + k0 + col8 * 8]);
            *reinterpret_cast<short8*>(&Bs[row * 64 + ((col8 * 8) ^ ((row & 7) << 3))]) = v;
        }
        __syncthreads();
        for (int kk = 0; kk < 2; ++kk) {
            int kof = kk * 32 + hi * 8;
            int sw = (ln & 7) << 3;
            short8 af[4], bf[4];
            for (int mf = 0; mf < 4; ++mf)
                af[mf] = *reinterpret_cast<const short8*>(&As[(wr * 64 + mf * 16 + ln) * 64 + (kof ^ sw)]);
            for (int nf = 0; nf < 4; ++nf)
                bf[nf] = *reinterpret_cast<const short8*>(&Bs[(wc * 64 + nf * 16 + ln) * 64 + (kof ^ sw)]);
            for (int mf = 0; mf < 4; ++mf)
                for (int nf = 0; nf < 4; ++nf)
                    acc[mf][nf] = __builtin_amdgcn_mfma_f32_16x16x32_bf16(af[mf], bf[nf], acc[mf][nf], 0, 0, 0);
        }
    }
    __syncthreads();

    if (w < 2) {
        short* O = (w == 0) ? Qb : Kb;
        for (int mf = 0; mf < 4; ++mf)
            for (int nf = 0; nf < 4; ++nf)
                for (int j = 0; j < 4; ++j) {
                    int row = m0 + wr * 64 + mf * 16 + hi * 4 + j;
                    int col = n0 + wc * 64 + nf * 16 + ln;
                    O[(size_t)row * 512 + col] = f2bf(sigm(acc[mf][nf][j]));
                }
    } else {
        for (int mf = 0; mf < 4; ++mf)
            for (int nf = 0; nf < 4; ++nf)
                for (int j = 0; j < 4; ++j) {
                    int ml = wr * 64 + mf * 16 + hi * 4 + j;       // s-local
                    int nl = wc * 64 + nf * 16 + ln;               // d-local
                    SMEM[nl * 128 + (ml ^ ((nl & 7) << 3))] = f2bf(sigm(acc[mf][nf][j]));
                }
        __syncthreads();
        int bb = m0 >> 11;
        int s0 = m0 & 2047;
        int d = tid >> 1, h = tid & 1;
        for (int i = 0; i < 8; ++i) {
            int s8 = h * 64 + i * 8;
            short8 v = *reinterpret_cast<const short8*>(&SMEM[d * 128 + (s8 ^ ((d & 7) << 3))]);
            *reinterpret_cast<short8*>(&VtG[((size_t)(bb * 512 + n0 + d)) * 2048 + s0 + s8]) = v;
        }
    }
}

// ---------------------------------------------------------------- K3: attention
// 256 blocks: b = bid&7 (XCD affinity), t = bid>>3 (q-tile of 64 rows), nsteps=t+1.
// 8 waves: QK^T frags (frp=w>>2 -> q-frag rows 2frp,2frp+1; fc=w&3); PV d-slice w*64.
// Staging via global_load_lds (linear LDS dest, inverse-swizzled global src).
__global__ __launch_bounds__(512, 2) void attn_kernel(
    const short* __restrict__ Qb, const short* __restrict__ Kb, const short* __restrict__ VtG,
    float* __restrict__ Out)
{
    __shared__ short Ks[64 * 512];     // [kv][k]  swizzled: col c holds K[r][c ^ ((r&7)<<3)]
    __shared__ short Vts[512 * 64];    // [d][kv]  swizzled likewise
    __shared__ short Ps[64 * 64];      // [q][kv]  bf16 swizzled
    __shared__ float lsum[4][64];      // per-fc row partial sums

    const float scale = 0.044194173824159216f;   // 1/sqrt(512)

    int bid = blockIdx.x;
    int b = bid & 7, t = bid >> 3;
    int q0 = t * 64;
    int nsteps = t + 1;

    int tid = threadIdx.x;
    int w = tid >> 6, lane = tid & 63;
    int ln = lane & 15, hi = lane >> 4;
    int frp = w >> 2, fc = w & 3;

    const short* Kbb = Kb  + (size_t)b * 2048 * 512;
    const short* Vbb = VtG + (size_t)b * 512 * 2048;

    if (tid < 256) ((float*)lsum)[tid] = 0.f;

    // Q fragments in registers: 2 q-frags x 16 k-steps (128 VGPR)
    short8 qf0[16], qf1[16];
    {
        const short* qr0 = Qb + (size_t)b * 2048 * 512 + (size_t)(q0 + (frp * 2 + 0) * 16 + ln) * 512 + hi * 8;
        const short* qr1 = qr0 + 16 * 512;
#pragma unroll
        for (int ks = 0; ks < 16; ++ks) {
            qf0[ks] = *reinterpret_cast<const short8*>(qr0 + ks * 32);
            qf1[ks] = *reinterpret_cast<const short8*>(qr1 + ks * 32);
        }
    }

    f32x4 acco[4][4];
#pragma unroll
    for (int i = 0; i < 4; ++i)
#pragma unroll
        for (int j = 0; j < 4; ++j) acco[i][j] = {0.f, 0.f, 0.f, 0.f};

    // staging lambdas: 8 gload_lds per wave each (1 KB per instruction)
    auto stageK = [&](int kt) {
#pragma unroll
        for (int j = 0; j < 8; ++j) {
            int r = w * 8 + j;
            const short* src = Kbb + (size_t)(kt * 64 + r) * 512 + ((lane * 8) ^ ((r & 7) << 3));
            gload_lds16(src, &Ks[r * 512]);
        }
    };
    auto stageV = [&](int kt) {
#pragma unroll
        for (int j = 0; j < 8; ++j) {
            int d0 = w * 64 + j * 8;
            int d = d0 + (lane >> 3);
            const short* src = Vbb + (size_t)d * 2048 + kt * 64 + (((lane & 7) * 8) ^ ((d & 7) << 3));
            gload_lds16(src, &Vts[d0 * 64]);
        }
    };

    // prologue: K(0) then V(0)  -> 16 outstanding per wave
    stageK(0);
    stageV(0);

    for (int kt = 0; kt < nsteps; ++kt) {
        int kv0 = kt * 64;
        SYNC_VM8();                       // K(kt) staged (V(kt) still in flight)

        // ---- QK^T: full K=512, one shared K-frag read feeds both q-frags
        f32x4 sacc0 = {0.f, 0.f, 0.f, 0.f}, sacc1 = {0.f, 0.f, 0.f, 0.f};
        {
            const short* kbase = &Ks[(fc * 16 + ln) * 512];
            int sw = (ln & 7) << 3;
            __builtin_amdgcn_s_setprio(1);
#pragma unroll
            for (int ks = 0; ks < 16; ++ks) {
                short8 kf = *reinterpret_cast<const short8*>(&kbase[(ks * 32 + hi * 8) ^ sw]);
                sacc0 = __builtin_amdgcn_mfma_f32_16x16x32_bf16(qf0[ks], kf, sacc0, 0, 0, 0);
                sacc1 = __builtin_amdgcn_mfma_f32_16x16x32_bf16(qf1[ks], kf, sacc1, 0, 0, 0);
            }
            __builtin_amdgcn_s_setprio(0);
        }
        BAR();                            // all waves done reading Ks

        if (kt + 1 < nsteps) stageK(kt + 1);   // K(t+1) loads during softmax+PV

        // ---- softmax: mask (strict j<i), exp, P->LDS bf16, row-sum partials
        {
            int jcol = kv0 + fc * 16 + ln;
#pragma unroll
            for (int g = 0; g < 2; ++g) {
                const f32x4& sa = g ? sacc1 : sacc0;
                float ps[4];
#pragma unroll
                for (int j = 0; j < 4; ++j) {
                    int rl = (frp * 2 + g) * 16 + hi * 4 + j;
                    int irow = q0 + rl;
                    float p = (jcol < irow) ? __expf(sa[j] * scale) : 0.f;
                    short h = f2bf(p);
                    Ps[rl * 64 + ((fc * 16 + ln) ^ ((rl & 7) << 3))] = h;
                    ps[j] = bf2f(h);
                }
#pragma unroll
                for (int j = 0; j < 4; ++j) {
                    float s = ps[j];
                    s += __shfl_xor(s, 1);
                    s += __shfl_xor(s, 2);
                    s += __shfl_xor(s, 4);
                    s += __shfl_xor(s, 8);
                    if (ln == 0) lsum[fc][(frp * 2 + g) * 16 + hi * 4 + j] += s;
                }
            }
        }

        if (kt + 1 < nsteps) { SYNC_VM8(); } else { SYNC_VM0(); }   // V(kt) staged + Ps visible

        // ---- PV: O[64][w*64..+64] += P[64][64] * V[64][slice]
        __builtin_amdgcn_s_setprio(1);
#pragma unroll
        for (int kst = 0; kst < 2; ++kst) {
            short8 pa[4];
#pragma unroll
            for (int rf = 0; rf < 4; ++rf) {
                int ar = rf * 16 + ln;
                pa[rf] = *reinterpret_cast<const short8*>(
                    &Ps[ar * 64 + ((kst * 32 + hi * 8) ^ ((ar & 7) << 3))]);
            }
#pragma unroll
            for (int cf = 0; cf < 4; ++cf) {
                int d = w * 64 + cf * 16 + ln;
                short8 vb = *reinterpret_cast<const short8*>(
                    &Vts[d * 64 + ((kst * 32 + hi * 8) ^ ((d & 7) << 3))]);
#pragma unroll
                for (int rf = 0; rf < 4; ++rf)
                    acco[rf][cf] = __builtin_amdgcn_mfma_f32_16x16x32_bf16(pa[rf], vb, acco[rf][cf], 0, 0, 0);
            }
        }
        __builtin_amdgcn_s_setprio(0);
        BAR();                            // Vts + Ps free

        if (kt + 1 < nsteps) stageV(kt + 1);   // V(t+1) loads during next QK^T
    }

    // ---- normalize + store (row 0 -> zeros)
#pragma unroll
    for (int rf = 0; rf < 4; ++rf)
#pragma unroll
        for (int j = 0; j < 4; ++j) {
            int rl = rf * 16 + hi * 4 + j;
            int i = q0 + rl;
            float denom = lsum[0][rl] + lsum[1][rl] + lsum[2][rl] + lsum[3][rl];
            float rd = (i == 0) ? 0.f : 1.0f / denom;
            float* orow = Out + ((size_t)b * 2048 + i) * 512 + w * 64 + ln;
#pragma unroll
            for (int cf = 0; cf < 4; ++cf)
                orow[cf * 16] = acco[rf][cf][j] * rd;
        }
}

// ---------------------------------------------------------------- launch
extern "C" void kernel_launch(void* const* d_in, const int* in_sizes, int n_in,
                              void* d_out, int out_size, void* d_ws, size_t ws_size,
                              hipStream_t stream) {
    const float* X  = (const float*)d_in[0];
    const float* Wq = (const float*)d_in[1];
    const float* Wv = (const float*)d_in[2];
    const float* Wk = (const float*)d_in[3];
    float* Out = (float*)d_out;

    char* ws = (char*)d_ws;
    const size_t WT_BYTES = (size_t)3 * 512 * 512 * 2;        // 1.5 MB
    const size_t MAT_BYTES = (size_t)16384 * 512 * 2;         // 16 MB each
    short* Wt = (short*)ws;
    short* Qb = (short*)(ws + WT_BYTES);
    short* Kb = (short*)(ws + WT_BYTES + MAT_BYTES);
    short* Vt = (short*)(ws + WT_BYTES + 2 * MAT_BYTES);

    prep_weights<<<192, 256, 0, stream>>>(Wq, Wv, Wk, Wt);
    qkv_gemm<<<1536, 256, 0, stream>>>(X, Wt, Qb, Kb, Vt);
    attn_kernel<<<256, 512, 0, stream>>>(Qb, Kb, Vt, Out);
}

// Round 4
// 261.320 us; speedup vs baseline: 1.3332x; 1.3332x over previous
//
#include <hip/hip_runtime.h>
#include <stdint.h>

// Round 4:
//  attn: block owns tile pair {p, 63-p} (32 rows each) with a MERGED kv loop:
//        one K/V stage per step shared by both tiles (halves staging per unit work).
//        Waves 0-3 compute tile A=p, waves 4-7 tile B=63-p; each wave holds ONE
//        16-row Q-frag (64 VGPR) -> no AGPR shuffling (R3's failure).
//        Reg-staging pipeline identical to proven R2 (loads issued right after
//        stage-write barrier, consumed next step; BAR = lgkmcnt-only barrier).
//  gemm/prep: reverted to R2 exactly (R3's XCD remap regressed +13us).

typedef __attribute__((ext_vector_type(4))) float f32x4;
typedef __attribute__((ext_vector_type(8))) short short8;
typedef __attribute__((ext_vector_type(4))) short short4b;

__device__ __forceinline__ short f2bf(float f) {
    union { float f; uint32_t u; } v; v.f = f;
    uint32_t r = (v.u + 0x7FFFu + ((v.u >> 16) & 1u)) >> 16;   // RNE
    return (short)r;
}
__device__ __forceinline__ float bf2f(short s) {
    union { uint32_t u; float f; } v; v.u = ((uint32_t)(uint16_t)s) << 16; return v.f;
}
__device__ __forceinline__ float sigm(float x) { return 1.0f / (1.0f + __expf(-x)); }

// barrier WITHOUT vmcnt drain: LDS writes visible, global prefetches stay in flight
#define BAR() asm volatile("s_waitcnt lgkmcnt(0)\n\ts_barrier" ::: "memory")

// ---------------------------------------------------------------- K1: weights
__global__ __launch_bounds__(256) void prep_weights(
    const float* __restrict__ Wq, const float* __restrict__ Wv, const float* __restrict__ Wk,
    short* __restrict__ Wt)
{
    __shared__ float T[64 * 68];
    int bid = blockIdx.x;
    int w = bid >> 6;                 // 0..2
    int tile = bid & 63;
    int n0 = (tile & 7) * 64;
    int k0 = (tile >> 3) * 64;
    const float* W = (w == 0) ? Wq : (w == 1) ? Wv : Wk;
    int t = threadIdx.x;
    int tr = t >> 4, tc = t & 15;
    for (int rr = 0; rr < 4; ++rr) {
        int row = rr * 16 + tr;       // k-local
        float4 v = *reinterpret_cast<const float4*>(&W[(size_t)(k0 + row) * 512 + n0 + tc * 4]);
        T[row * 68 + tc * 4 + 0] = v.x;
        T[row * 68 + tc * 4 + 1] = v.y;
        T[row * 68 + tc * 4 + 2] = v.z;
        T[row * 68 + tc * 4 + 3] = v.w;
    }
    __syncthreads();
    for (int wr = 0; wr < 4; ++wr) {
        int nl = wr * 16 + tr;        // n-local
        short4b o;
        for (int i = 0; i < 4; ++i) o[i] = f2bf(T[(tc * 4 + i) * 68 + nl]);
        *reinterpret_cast<short4b*>(&Wt[((size_t)(w * 512 + n0 + nl)) * 512 + k0 + tc * 4]) = o;
    }
}

// ---------------------------------------------------------------- K2: QKV GEMM (R2 version)
__global__ __launch_bounds__(256) void qkv_gemm(
    const float* __restrict__ X,     // [16384][512] fp32
    const short* __restrict__ Wt,    // [3][512 n][512 k] bf16
    short* __restrict__ Qb, short* __restrict__ Kb, short* __restrict__ VtG)
{
    __shared__ short SMEM[128 * 128];
    short* As = SMEM;
    short* Bs = SMEM + 128 * 64;

    int bx = blockIdx.x;
    int mt = bx & 127;
    int y = bx >> 7;
    int w = y >> 2, nt = y & 3;
    int m0 = mt * 128, n0 = nt * 128;

    int tid = threadIdx.x;
    int wid = tid >> 6, lane = tid & 63;
    int wr = wid >> 1, wc = wid & 1;
    int ln = lane & 15, hi = lane >> 4;

    f32x4 acc[4][4];
    for (int i = 0; i < 4; ++i) for (int j = 0; j < 4; ++j) acc[i][j] = {0.f, 0.f, 0.f, 0.f};

    const short* WtW = Wt + (size_t)w * 512 * 512;

    for (int ko = 0; ko < 8; ++ko) {
        int k0 = ko * 64;
        __syncthreads();
        for (int j = 0; j < 8; ++j) {
            int c = j * 256 + tid;
            int row = c >> 4, col4 = c & 15;
            float4 v = *reinterpret_cast<const float4*>(&X[(size_t)(m0 + row) * 512 + k0 + col4 * 4]);
            short4b s;
            s[0] = f2bf(v.x); s[1] = f2bf(v.y); s[2] = f2bf(v.z); s[3] = f2bf(v.w);
            *reinterpret_cast<short4b*>(&As[row * 64 + ((col4 * 4) ^ ((row & 7) << 3))]) = s;
        }
        for (int j = 0; j < 4; ++j) {
            int c = j * 256 + tid;
            int row = c >> 3, col8 = c & 7;
            short8 v = *reinterpret_cast<const short8*>(&WtW[(size_t)(n0 + row) * 512 + k0 + col8 * 8]);
            *reinterpret_cast<short8*>(&Bs[row * 64 + ((col8 * 8) ^ ((row & 7) << 3))]) = v;
        }
        __syncthreads();
        for (int kk = 0; kk < 2; ++kk) {
            int kof = kk * 32 + hi * 8;
            int sw = (ln & 7) << 3;
            short8 af[4], bf[4];
            for (int mf = 0; mf < 4; ++mf)
                af[mf] = *reinterpret_cast<const short8*>(&As[(wr * 64 + mf * 16 + ln) * 64 + (kof ^ sw)]);
            for (int nf = 0; nf < 4; ++nf)
                bf[nf] = *reinterpret_cast<const short8*>(&Bs[(wc * 64 + nf * 16 + ln) * 64 + (kof ^ sw)]);
            for (int mf = 0; mf < 4; ++mf)
                for (int nf = 0; nf < 4; ++nf)
                    acc[mf][nf] = __builtin_amdgcn_mfma_f32_16x16x32_bf16(af[mf], bf[nf], acc[mf][nf], 0, 0, 0);
        }
    }
    __syncthreads();

    if (w < 2) {
        short* O = (w == 0) ? Qb : Kb;
        for (int mf = 0; mf < 4; ++mf)
            for (int nf = 0; nf < 4; ++nf)
                for (int j = 0; j < 4; ++j) {
                    int row = m0 + wr * 64 + mf * 16 + hi * 4 + j;
                    int col = n0 + wc * 64 + nf * 16 + ln;
                    O[(size_t)row * 512 + col] = f2bf(sigm(acc[mf][nf][j]));
                }
    } else {
        for (int mf = 0; mf < 4; ++mf)
            for (int nf = 0; nf < 4; ++nf)
                for (int j = 0; j < 4; ++j) {
                    int ml = wr * 64 + mf * 16 + hi * 4 + j;       // s-local
                    int nl = wc * 64 + nf * 16 + ln;               // d-local
                    SMEM[nl * 128 + (ml ^ ((nl & 7) << 3))] = f2bf(sigm(acc[mf][nf][j]));
                }
        __syncthreads();
        int bb = m0 >> 11;
        int s0 = m0 & 2047;
        int d = tid >> 1, h = tid & 1;
        for (int i = 0; i < 8; ++i) {
            int s8 = h * 64 + i * 8;
            short8 v = *reinterpret_cast<const short8*>(&SMEM[d * 128 + (s8 ^ ((d & 7) << 3))]);
            *reinterpret_cast<short8*>(&VtG[((size_t)(bb * 512 + n0 + d)) * 2048 + s0 + s8]) = v;
        }
    }
}

// ---------------------------------------------------------------- K3: attention
// 256 blocks: b=bid&7 (XCD affinity), p=bid>>3 in [0,32). Tiles A=p, B=63-p (32 rows each).
// Merged kv loop: one staged K/V tile per step serves both tiles.
// Waves 0-3 -> tile A, waves 4-7 -> tile B. Within group: u=w&3, qfrag r=u>>1 (16 rows),
// kv-half h=u&1 (cols h*32..h*32+32, two 16-col frags). PV: wave owns d-slice u*128..+128.
__global__ __launch_bounds__(512, 2) void attn_kernel(
    const short* __restrict__ Qb, const short* __restrict__ Kb, const short* __restrict__ VtG,
    float* __restrict__ Out)
{
    __shared__ short Ks[64 * 512];     // [kv][k]  col c holds K[r][c ^ ((r&7)<<3)]
    __shared__ short Vts[512 * 64];    // [d][kv]  swizzled likewise
    __shared__ short Ps[2][32 * 64];   // per-group [q][kv] bf16 swizzled
    __shared__ float lsum[2][2][32];   // [group][kv-half][row]

    const float scale = 0.044194173824159216f;   // 1/sqrt(512)

    int bid = blockIdx.x;
    int b = bid & 7, p = bid >> 3;
    int tA = p, tB = 63 - p;
    int nA = (32 * tA + 30) / 64 + 1;  // kv steps tile A needs
    int nB = (32 * tB + 30) / 64 + 1;  // kv steps tile B needs (>= nA)

    int tid = threadIdx.x;
    int w = tid >> 6, lane = tid & 63;
    int ln = lane & 15, hi = lane >> 4;
    int g = w >> 2, u = w & 3;
    int r = u >> 1, h = u & 1;
    int tg = g ? tB : tA;
    int q0 = tg * 32;
    int nsteps_g = g ? nB : nA;

    const short* Kbb = Kb  + (size_t)b * 2048 * 512;
    const short* Vbb = VtG + (size_t)b * 512 * 2048;

    if (tid < 128) ((float*)lsum)[tid] = 0.f;

    // Q fragment: 16 rows (q0 + r*16 + ln), full K=512 -> 64 VGPR
    short8 qf[16];
    {
        const short* qrow = Qb + (size_t)b * 2048 * 512 + (size_t)(q0 + r * 16 + ln) * 512 + hi * 8;
#pragma unroll
        for (int ks = 0; ks < 16; ++ks)
            qf[ks] = *reinterpret_cast<const short8*>(qrow + ks * 32);
    }

    f32x4 acco[2][8];                  // [rf][cf] -> rows rf*16+, cols u*128+cf*16+
#pragma unroll
    for (int i = 0; i < 2; ++i)
#pragma unroll
        for (int j = 0; j < 8; ++j) acco[i][j] = {0.f, 0.f, 0.f, 0.f};

    short8 kreg[8], vreg[8];
    auto loadK = [&](int kt) {
#pragma unroll
        for (int j = 0; j < 8; ++j) {
            int c = j * 512 + tid;
            int row = c >> 6, c8 = c & 63;
            kreg[j] = *reinterpret_cast<const short8*>(&Kbb[(size_t)(kt * 64 + row) * 512 + c8 * 8]);
        }
    };
    auto loadV = [&](int kt) {
#pragma unroll
        for (int j = 0; j < 8; ++j) {
            int c = j * 512 + tid;
            int d = c >> 3, c8 = c & 7;
            vreg[j] = *reinterpret_cast<const short8*>(&Vbb[(size_t)d * 2048 + kt * 64 + c8 * 8]);
        }
    };

    loadK(0);
    loadV(0);

    for (int kt = 0; kt < nB; ++kt) {
        BAR();                                 // prev step's LDS reads done
        // stage regs -> LDS (compiler inserts vmcnt waits on kreg/vreg)
#pragma unroll
        for (int j = 0; j < 8; ++j) {
            int c = j * 512 + tid;
            int row = c >> 6, sc = (c & 63) * 8;
            *reinterpret_cast<short8*>(&Ks[row * 512 + (sc ^ ((row & 7) << 3))]) = kreg[j];
        }
#pragma unroll
        for (int j = 0; j < 8; ++j) {
            int c = j * 512 + tid;
            int d = c >> 3, sc = (c & 7) * 8;
            *reinterpret_cast<short8*>(&Vts[d * 64 + (sc ^ ((d & 7) << 3))]) = vreg[j];
        }
        BAR();                                 // K/V visible
        if (kt + 1 < nB) { loadK(kt + 1); loadV(kt + 1); }   // overlap with compute

        bool act = (kt < nsteps_g);
        int kv0 = kt * 64;

        if (act) {
            // ---- QK^T: 2 kv-frags (h*32, h*32+16), full K=512
            f32x4 s0 = {0.f, 0.f, 0.f, 0.f}, s1 = {0.f, 0.f, 0.f, 0.f};
            {
                const short* k0b = &Ks[(h * 32 + ln) * 512];
                const short* k1b = k0b + 16 * 512;
                int sw = (ln & 7) << 3;
                __builtin_amdgcn_s_setprio(1);
#pragma unroll
                for (int ks = 0; ks < 16; ++ks) {
                    int koff = (ks * 32 + hi * 8) ^ sw;
                    short8 kf0 = *reinterpret_cast<const short8*>(&k0b[koff]);
                    short8 kf1 = *reinterpret_cast<const short8*>(&k1b[koff]);
                    s0 = __builtin_amdgcn_mfma_f32_16x16x32_bf16(qf[ks], kf0, s0, 0, 0, 0);
                    s1 = __builtin_amdgcn_mfma_f32_16x16x32_bf16(qf[ks], kf1, s1, 0, 0, 0);
                }
                __builtin_amdgcn_s_setprio(0);
            }
            // ---- softmax: mask strict j<i, exp, P->LDS bf16, row-sum partials
            {
                float psum[4] = {0.f, 0.f, 0.f, 0.f};
#pragma unroll
                for (int c = 0; c < 2; ++c) {
                    const f32x4& sa = c ? s1 : s0;
                    int jcol = kv0 + (h * 2 + c) * 16 + ln;
#pragma unroll
                    for (int j = 0; j < 4; ++j) {
                        int rl = r * 16 + hi * 4 + j;
                        int irow = q0 + rl;
                        float pfl = (jcol < irow) ? __expf(sa[j] * scale) : 0.f;
                        short hs = f2bf(pfl);
                        Ps[g][rl * 64 + (((h * 2 + c) * 16 + ln) ^ ((rl & 7) << 3))] = hs;
                        psum[j] += bf2f(hs);
                    }
                }
#pragma unroll
                for (int j = 0; j < 4; ++j) {
                    float s = psum[j];
                    s += __shfl_xor(s, 1);
                    s += __shfl_xor(s, 2);
                    s += __shfl_xor(s, 4);
                    s += __shfl_xor(s, 8);
                    if (ln == 0) lsum[g][h][r * 16 + hi * 4 + j] += s;   // unique writer
                }
            }
        }
        BAR();                                 // Ps visible

        if (act) {
            // ---- PV: O[32][u*128..+128] += P_g[32][64] * V[64][slice]
            __builtin_amdgcn_s_setprio(1);
#pragma unroll
            for (int kst = 0; kst < 2; ++kst) {
                short8 pa[2];
#pragma unroll
                for (int rf = 0; rf < 2; ++rf) {
                    int ar = rf * 16 + ln;
                    pa[rf] = *reinterpret_cast<const short8*>(
                        &Ps[g][ar * 64 + ((kst * 32 + hi * 8) ^ ((ar & 7) << 3))]);
                }
#pragma unroll
                for (int cf = 0; cf < 8; ++cf) {
                    int d = u * 128 + cf * 16 + ln;
                    short8 vb = *reinterpret_cast<const short8*>(
                        &Vts[d * 64 + ((kst * 32 + hi * 8) ^ ((d & 7) << 3))]);
                    acco[0][cf] = __builtin_amdgcn_mfma_f32_16x16x32_bf16(pa[0], vb, acco[0][cf], 0, 0, 0);
                    acco[1][cf] = __builtin_amdgcn_mfma_f32_16x16x32_bf16(pa[1], vb, acco[1][cf], 0, 0, 0);
                }
            }
            __builtin_amdgcn_s_setprio(0);
        }
        BAR();                                 // Ks/Vts/Ps free for next stage
    }

    // ---- normalize + store (row 0 of each batch -> zeros)
#pragma unroll
    for (int rf = 0; rf < 2; ++rf)
#pragma unroll
        for (int j = 0; j < 4; ++j) {
            int rl = rf * 16 + hi * 4 + j;
            int i = q0 + rl;
            float denom = lsum[g][0][rl] + lsum[g][1][rl];
            float rd = (i == 0) ? 0.f : 1.0f / denom;
            float* orow = Out + ((size_t)b * 2048 + i) * 512 + u * 128 + ln;
#pragma unroll
            for (int cf = 0; cf < 8; ++cf)
                orow[cf * 16] = acco[rf][cf][j] * rd;
        }
}

// ---------------------------------------------------------------- launch
extern "C" void kernel_launch(void* const* d_in, const int* in_sizes, int n_in,
                              void* d_out, int out_size, void* d_ws, size_t ws_size,
                              hipStream_t stream) {
    const float* X  = (const float*)d_in[0];
    const float* Wq = (const float*)d_in[1];
    const float* Wv = (const float*)d_in[2];
    const float* Wk = (const float*)d_in[3];
    float* Out = (float*)d_out;

    char* ws = (char*)d_ws;
    const size_t WT_BYTES = (size_t)3 * 512 * 512 * 2;        // 1.5 MB
    const size_t MAT_BYTES = (size_t)16384 * 512 * 2;         // 16 MB each
    short* Wt = (short*)ws;
    short* Qb = (short*)(ws + WT_BYTES);
    short* Kb = (short*)(ws + WT_BYTES + MAT_BYTES);
    short* Vt = (short*)(ws + WT_BYTES + 2 * MAT_BYTES);

    prep_weights<<<192, 256, 0, stream>>>(Wq, Wv, Wk, Wt);
    qkv_gemm<<<1536, 256, 0, stream>>>(X, Wt, Qb, Kb, Vt);
    attn_kernel<<<256, 512, 0, stream>>>(Qb, Kb, Vt, Out);
}

// Round 5
// 198.993 us; speedup vs baseline: 1.7508x; 1.3132x over previous
//
#include <hip/hip_runtime.h>
#include <stdint.h>

// Round 5: attn rebuilt for 2 blocks/CU (m114 implicit overlap).
//  - 256-thr blocks (4 waves): 2 blocks/CU -> 2 waves/SIMD -> 256 VGPR budget (no spills)
//  - QBLK=32, KVBLK=32; K double-buffered in LDS via global_load_lds (counted vmcnt,
//    never drained mid-loop); V NOT staged (wave-exclusive d-slice, loaded L2->reg
//    directly as MFMA B-fragments); denominator accumulated in-register.
//  - LDS 67.8KB -> 2 blocks/CU. Grid 512: bid&255 -> (batch=idx&7, p=idx>>3),
//    bid>>8 selects tile p vs 63-p so co-resident blocks are load-balanced.
// K1/K2 unchanged (proven).

typedef __attribute__((ext_vector_type(4))) float f32x4;
typedef __attribute__((ext_vector_type(8))) short short8;
typedef __attribute__((ext_vector_type(4))) short short4b;

__device__ __forceinline__ short f2bf(float f) {
    union { float f; uint32_t u; } v; v.f = f;
    uint32_t r = (v.u + 0x7FFFu + ((v.u >> 16) & 1u)) >> 16;   // RNE
    return (short)r;
}
__device__ __forceinline__ float bf2f(short s) {
    union { uint32_t u; float f; } v; v.u = ((uint32_t)(uint16_t)s) << 16; return v.f;
}
__device__ __forceinline__ float sigm(float x) { return 1.0f / (1.0f + __expf(-x)); }

__device__ __forceinline__ void gload_lds16(const void* g, void* l) {
    __builtin_amdgcn_global_load_lds(
        (const __attribute__((address_space(1))) void*)g,
        (__attribute__((address_space(3))) void*)l, 16, 0, 0);
}

// ---------------------------------------------------------------- K1: weights
__global__ __launch_bounds__(256) void prep_weights(
    const float* __restrict__ Wq, const float* __restrict__ Wv, const float* __restrict__ Wk,
    short* __restrict__ Wt)
{
    __shared__ float T[64 * 68];
    int bid = blockIdx.x;
    int w = bid >> 6;                 // 0..2
    int tile = bid & 63;
    int n0 = (tile & 7) * 64;
    int k0 = (tile >> 3) * 64;
    const float* W = (w == 0) ? Wq : (w == 1) ? Wv : Wk;
    int t = threadIdx.x;
    int tr = t >> 4, tc = t & 15;
    for (int rr = 0; rr < 4; ++rr) {
        int row = rr * 16 + tr;       // k-local
        float4 v = *reinterpret_cast<const float4*>(&W[(size_t)(k0 + row) * 512 + n0 + tc * 4]);
        T[row * 68 + tc * 4 + 0] = v.x;
        T[row * 68 + tc * 4 + 1] = v.y;
        T[row * 68 + tc * 4 + 2] = v.z;
        T[row * 68 + tc * 4 + 3] = v.w;
    }
    __syncthreads();
    for (int wr = 0; wr < 4; ++wr) {
        int nl = wr * 16 + tr;        // n-local
        short4b o;
        for (int i = 0; i < 4; ++i) o[i] = f2bf(T[(tc * 4 + i) * 68 + nl]);
        *reinterpret_cast<short4b*>(&Wt[((size_t)(w * 512 + n0 + nl)) * 512 + k0 + tc * 4]) = o;
    }
}

// ---------------------------------------------------------------- K2: QKV GEMM
__global__ __launch_bounds__(256) void qkv_gemm(
    const float* __restrict__ X,     // [16384][512] fp32
    const short* __restrict__ Wt,    // [3][512 n][512 k] bf16
    short* __restrict__ Qb, short* __restrict__ Kb, short* __restrict__ VtG)
{
    __shared__ short SMEM[128 * 128];
    short* As = SMEM;
    short* Bs = SMEM + 128 * 64;

    int bx = blockIdx.x;
    int mt = bx & 127;
    int y = bx >> 7;
    int w = y >> 2, nt = y & 3;
    int m0 = mt * 128, n0 = nt * 128;

    int tid = threadIdx.x;
    int wid = tid >> 6, lane = tid & 63;
    int wr = wid >> 1, wc = wid & 1;
    int ln = lane & 15, hi = lane >> 4;

    f32x4 acc[4][4];
    for (int i = 0; i < 4; ++i) for (int j = 0; j < 4; ++j) acc[i][j] = {0.f, 0.f, 0.f, 0.f};

    const short* WtW = Wt + (size_t)w * 512 * 512;

    for (int ko = 0; ko < 8; ++ko) {
        int k0 = ko * 64;
        __syncthreads();
        for (int j = 0; j < 8; ++j) {
            int c = j * 256 + tid;
            int row = c >> 4, col4 = c & 15;
            float4 v = *reinterpret_cast<const float4*>(&X[(size_t)(m0 + row) * 512 + k0 + col4 * 4]);
            short4b s;
            s[0] = f2bf(v.x); s[1] = f2bf(v.y); s[2] = f2bf(v.z); s[3] = f2bf(v.w);
            *reinterpret_cast<short4b*>(&As[row * 64 + ((col4 * 4) ^ ((row & 7) << 3))]) = s;
        }
        for (int j = 0; j < 4; ++j) {
            int c = j * 256 + tid;
            int row = c >> 3, col8 = c & 7;
            short8 v = *reinterpret_cast<const short8*>(&WtW[(size_t)(n0 + row) * 512 + k0 + col8 * 8]);
            *reinterpret_cast<short8*>(&Bs[row * 64 + ((col8 * 8) ^ ((row & 7) << 3))]) = v;
        }
        __syncthreads();
        for (int kk = 0; kk < 2; ++kk) {
            int kof = kk * 32 + hi * 8;
            int sw = (ln & 7) << 3;
            short8 af[4], bf[4];
            for (int mf = 0; mf < 4; ++mf)
                af[mf] = *reinterpret_cast<const short8*>(&As[(wr * 64 + mf * 16 + ln) * 64 + (kof ^ sw)]);
            for (int nf = 0; nf < 4; ++nf)
                bf[nf] = *reinterpret_cast<const short8*>(&Bs[(wc * 64 + nf * 16 + ln) * 64 + (kof ^ sw)]);
            for (int mf = 0; mf < 4; ++mf)
                for (int nf = 0; nf < 4; ++nf)
                    acc[mf][nf] = __builtin_amdgcn_mfma_f32_16x16x32_bf16(af[mf], bf[nf], acc[mf][nf], 0, 0, 0);
        }
    }
    __syncthreads();

    if (w < 2) {
        short* O = (w == 0) ? Qb : Kb;
        for (int mf = 0; mf < 4; ++mf)
            for (int nf = 0; nf < 4; ++nf)
                for (int j = 0; j < 4; ++j) {
                    int row = m0 + wr * 64 + mf * 16 + hi * 4 + j;
                    int col = n0 + wc * 64 + nf * 16 + ln;
                    O[(size_t)row * 512 + col] = f2bf(sigm(acc[mf][nf][j]));
                }
    } else {
        for (int mf = 0; mf < 4; ++mf)
            for (int nf = 0; nf < 4; ++nf)
                for (int j = 0; j < 4; ++j) {
                    int ml = wr * 64 + mf * 16 + hi * 4 + j;       // s-local
                    int nl = wc * 64 + nf * 16 + ln;               // d-local
                    SMEM[nl * 128 + (ml ^ ((nl & 7) << 3))] = f2bf(sigm(acc[mf][nf][j]));
                }
        __syncthreads();
        int bb = m0 >> 11;
        int s0 = m0 & 2047;
        int d = tid >> 1, h = tid & 1;
        for (int i = 0; i < 8; ++i) {
            int s8 = h * 64 + i * 8;
            short8 v = *reinterpret_cast<const short8*>(&SMEM[d * 128 + (s8 ^ ((d & 7) << 3))]);
            *reinterpret_cast<short8*>(&VtG[((size_t)(bb * 512 + n0 + d)) * 2048 + s0 + s8]) = v;
        }
    }
}

// ---------------------------------------------------------------- K3: attention
// 512 blocks x 256 thr. idx=bid&255: b=idx&7 (XCD), p=idx>>3; tile t = (bid>>8)? 63-p : p.
// 4 waves: QK^T frag (fr=w>>1 q-rows, fc=w&1 kv-cols); PV d-slice w*128.
// K dbuf in LDS (gload_lds, counted vmcnt); V direct L2->reg; denom in-register.
__global__ __launch_bounds__(256, 2) void attn_kernel(
    const short* __restrict__ Qb, const short* __restrict__ Kb, const short* __restrict__ VtG,
    float* __restrict__ Out)
{
    __shared__ short Ks[2][32 * 512];  // [buf][kv][k]: col c holds K[r][c ^ ((r&7)<<3)]
    __shared__ short Ps[32 * 32];      // [q][kv]: chunk c8 stored at c8 ^ (r&3)
    __shared__ float lsum[2][32];      // [fc][row] final reduce only

    const float scale = 0.044194173824159216f;   // 1/sqrt(512)

    int bid = blockIdx.x;
    int idx = bid & 255;
    int b = idx & 7, p = idx >> 3;
    int t = (bid >> 8) ? (63 - p) : p;
    int q0 = t * 32;
    int nsteps = t + 1;

    int tid = threadIdx.x;
    int w = tid >> 6, lane = tid & 63;
    int ln = lane & 15, hi = lane >> 4;
    int fr = w >> 1, fc = w & 1;

    const short* Kbb = Kb + (size_t)b * 2048 * 512;
    const short* Vbb = VtG + (size_t)b * 512 * 2048 + (size_t)(w * 128 + ln) * 2048 + hi * 8;

    // Q fragment: rows q0 + fr*16 + ln, full K=512 (64 VGPR)
    short8 qf[16];
    {
        const short* qrow = Qb + (size_t)b * 2048 * 512 + (size_t)(q0 + fr * 16 + ln) * 512 + hi * 8;
#pragma unroll
        for (int ks = 0; ks < 16; ++ks)
            qf[ks] = *reinterpret_cast<const short8*>(qrow + ks * 32);
    }

    f32x4 acco[2][8];                  // [rf][cf]: rows rf*16+, cols w*128+cf*16+
#pragma unroll
    for (int i = 0; i < 2; ++i)
#pragma unroll
        for (int j = 0; j < 8; ++j) acco[i][j] = {0.f, 0.f, 0.f, 0.f};
    float dsum[4] = {0.f, 0.f, 0.f, 0.f};

    // K staging: 32x512 bf16 = 32KB; 8 gload_lds/thread; wave-uniform LDS row 4j+w
#define STAGE_K(kt, buf)                                                          \
    {                                                                             \
        _Pragma("unroll")                                                         \
        for (int j = 0; j < 8; ++j) {                                             \
            int row = j * 4 + w;                                                  \
            const short* src = Kbb + (size_t)((kt) * 32 + row) * 512              \
                               + ((lane * 8) ^ ((row & 7) << 3));                 \
            gload_lds16(src, &Ks[buf][row * 512]);                                \
        }                                                                         \
    }

    STAGE_K(0, 0);

    int cur = 0;
    for (int kt = 0; kt < nsteps; ++kt) {
        int kv0 = kt * 32;

        // V fragments for this step: B-frag, col d = w*128+cf*16+ln, k-rows kv0+hi*8..+8
        short8 vb[8];
#pragma unroll
        for (int cf = 0; cf < 8; ++cf)
            vb[cf] = *reinterpret_cast<const short8*>(Vbb + (size_t)(cf * 16) * 2048 + kv0);

        // barrier1: K(kt) staged (8 vb loads remain in flight)
        asm volatile("s_waitcnt vmcnt(8)\n\ts_barrier" ::: "memory");

        if (kt + 1 < nsteps) STAGE_K(kt + 1, cur ^ 1);   // into other buffer, flies over compute

        // ---- QK^T: frag (fr, fc), full K=512
        f32x4 sacc = {0.f, 0.f, 0.f, 0.f};
        {
            const short* kbase = &Ks[cur][(fc * 16 + ln) * 512];
            int sw = (ln & 7) << 3;
            __builtin_amdgcn_s_setprio(1);
#pragma unroll
            for (int ks = 0; ks < 16; ++ks) {
                short8 kf = *reinterpret_cast<const short8*>(&kbase[(ks * 32 + hi * 8) ^ sw]);
                sacc = __builtin_amdgcn_mfma_f32_16x16x32_bf16(qf[ks], kf, sacc, 0, 0, 0);
            }
            __builtin_amdgcn_s_setprio(0);
        }

        // ---- softmax: strict mask j<i, exp, P->LDS bf16, in-reg denom
        {
            int jc = fc * 16 + ln;                 // local col 0..31
            int jcol = kv0 + jc;
#pragma unroll
            for (int j = 0; j < 4; ++j) {
                int rl = fr * 16 + hi * 4 + j;
                int irow = q0 + rl;
                float pfl = (jcol < irow) ? __expf(sacc[j] * scale) : 0.f;
                short hs = f2bf(pfl);
                Ps[rl * 32 + ((((jc >> 3) ^ (rl & 3)) << 3) | (jc & 7))] = hs;
                dsum[j] += bf2f(hs);               // numerator/denominator consistent
            }
        }
        // barrier2: Ps visible (K(kt+1) gload_lds stay in flight; lgkm only)
        asm volatile("s_waitcnt lgkmcnt(0)\n\ts_barrier" ::: "memory");

        // vb ready (8 newer gload_lds may remain)
        if (kt + 1 < nsteps) {
            asm volatile("s_waitcnt vmcnt(8)" ::: "memory");
        } else {
            asm volatile("s_waitcnt vmcnt(0)" ::: "memory");
        }

        // ---- PV: O[32][w*128..+128] += P[32][32] * V[32][slice]   (K=32: one MFMA each)
        __builtin_amdgcn_s_setprio(1);
        {
            short8 pa[2];
#pragma unroll
            for (int rf = 0; rf < 2; ++rf) {
                int ar = rf * 16 + ln;
                pa[rf] = *reinterpret_cast<const short8*>(
                    &Ps[ar * 32 + ((hi ^ (ar & 3)) << 3)]);
            }
#pragma unroll
            for (int cf = 0; cf < 8; ++cf) {
                acco[0][cf] = __builtin_amdgcn_mfma_f32_16x16x32_bf16(pa[0], vb[cf], acco[0][cf], 0, 0, 0);
                acco[1][cf] = __builtin_amdgcn_mfma_f32_16x16x32_bf16(pa[1], vb[cf], acco[1][cf], 0, 0, 0);
            }
        }
        __builtin_amdgcn_s_setprio(0);

        cur ^= 1;
    }

    // ---- denominator: reduce dsum over 16 lanes (ln), publish per fc-half, combine
#pragma unroll
    for (int j = 0; j < 4; ++j) {
        float s = dsum[j];
        s += __shfl_xor(s, 1);
        s += __shfl_xor(s, 2);
        s += __shfl_xor(s, 4);
        s += __shfl_xor(s, 8);
        if (ln == 0) lsum[fc][fr * 16 + hi * 4 + j] = s;
    }
    __syncthreads();

    // ---- normalize + store (row 0 of each batch -> zeros)
#pragma unroll
    for (int rf = 0; rf < 2; ++rf)
#pragma unroll
        for (int j = 0; j < 4; ++j) {
            int rl = rf * 16 + hi * 4 + j;
            int i = q0 + rl;
            float denom = lsum[0][rl] + lsum[1][rl];
            float rd = (i == 0) ? 0.f : 1.0f / denom;
            float* orow = Out + ((size_t)b * 2048 + i) * 512 + w * 128 + ln;
#pragma unroll
            for (int cf = 0; cf < 8; ++cf)
                orow[cf * 16] = acco[rf][cf][j] * rd;
        }
#undef STAGE_K
}

// ---------------------------------------------------------------- launch
extern "C" void kernel_launch(void* const* d_in, const int* in_sizes, int n_in,
                              void* d_out, int out_size, void* d_ws, size_t ws_size,
                              hipStream_t stream) {
    const float* X  = (const float*)d_in[0];
    const float* Wq = (const float*)d_in[1];
    const float* Wv = (const float*)d_in[2];
    const float* Wk = (const float*)d_in[3];
    float* Out = (float*)d_out;

    char* ws = (char*)d_ws;
    const size_t WT_BYTES = (size_t)3 * 512 * 512 * 2;        // 1.5 MB
    const size_t MAT_BYTES = (size_t)16384 * 512 * 2;         // 16 MB each
    short* Wt = (short*)ws;
    short* Qb = (short*)(ws + WT_BYTES);
    short* Kb = (short*)(ws + WT_BYTES + MAT_BYTES);
    short* Vt = (short*)(ws + WT_BYTES + 2 * MAT_BYTES);

    prep_weights<<<192, 256, 0, stream>>>(Wq, Wv, Wk, Wt);
    qkv_gemm<<<1536, 256, 0, stream>>>(X, Wt, Qb, Kb, Vt);
    attn_kernel<<<512, 256, 0, stream>>>(Qb, Kb, Vt, Out);
}